// Round 1
// baseline (235.204 us; speedup 1.0000x reference)
//
#include <hip/hip_runtime.h>
#include <math.h>

// ---------------------------------------------------------------------------
// Host-side: build the stiffness matrix C = inv(Ci) in double precision,
// exactly mirroring the reference's np.linalg.inv (Ci is block-diagonal:
// dense 3x3 block + diagonal shear block, so the inverse is block-diagonal
// too; the shear diagonal inverts to Ep/(2*(1+vp)) = 0.075).
// ---------------------------------------------------------------------------
struct CParams {
    float b[3][3];  // inverse of the upper-left 3x3 compliance block
    float s;        // shear stiffness diagonal = Ep / (2*(1+vp))
};

static CParams make_C() {
    const double vp = 0.4, Ep = 0.21;
    double A[3][3] = {
        {1.0 / Ep, -vp / Ep, -vp / Ep},
        {-vp / Ep, 1.0 / Ep, -vp / Ep},
        {-vp,      -vp,      1.0 / Ep},   // note: -vp, NOT -vp/Ep (faithful)
    };
    double inv[3][3] = {{1, 0, 0}, {0, 1, 0}, {0, 0, 1}};
    // Gauss-Jordan with partial pivoting
    for (int col = 0; col < 3; ++col) {
        int piv = col;
        for (int r = col + 1; r < 3; ++r)
            if (fabs(A[r][col]) > fabs(A[piv][col])) piv = r;
        if (piv != col) {
            for (int c = 0; c < 3; ++c) {
                double t = A[col][c]; A[col][c] = A[piv][c]; A[piv][c] = t;
                t = inv[col][c]; inv[col][c] = inv[piv][c]; inv[piv][c] = t;
            }
        }
        double d = A[col][col];
        for (int c = 0; c < 3; ++c) { A[col][c] /= d; inv[col][c] /= d; }
        for (int r = 0; r < 3; ++r) {
            if (r == col) continue;
            double f = A[r][col];
            for (int c = 0; c < 3; ++c) {
                A[r][c] -= f * A[col][c];
                inv[r][c] -= f * inv[col][c];
            }
        }
    }
    CParams p;
    for (int i = 0; i < 3; ++i)
        for (int j = 0; j < 3; ++j)
            p.b[i][j] = (float)inv[i][j];
    p.s = (float)(Ep / (2.0 * (1.0 + vp)));
    return p;
}

static const CParams g_C = make_C();

// ---------------------------------------------------------------------------
// Main reduction kernel: grid-stride over packets of 4 points.
// Per packet: 3 float4 from each grad array (coalesced 16B/lane) + 1 float4
// of gt_sdf. Per-thread partials -> wave shuffle reduce -> LDS -> 1 atomic
// pair per block.
// ---------------------------------------------------------------------------
__global__ __launch_bounds__(256) void biomech_reduce(
    const float* __restrict__ gu, const float* __restrict__ gv,
    const float* __restrict__ gw, const float* __restrict__ gs,
    float* __restrict__ ws, int npack, int n, CParams C)
{
    const float4* u4 = (const float4*)gu;
    const float4* v4 = (const float4*)gv;
    const float4* w4 = (const float4*)gw;
    const float4* s4 = (const float4*)gs;

    float sumq2 = 0.0f;
    float cnt   = 0.0f;

    const int stride = gridDim.x * blockDim.x;
    for (int p = blockIdx.x * blockDim.x + threadIdx.x; p < npack; p += stride) {
        float4 ua = u4[3 * p], ub = u4[3 * p + 1], uc = u4[3 * p + 2];
        float4 va = v4[3 * p], vb = v4[3 * p + 1], vc = v4[3 * p + 2];
        float4 wa = w4[3 * p], wb = w4[3 * p + 1], wc = w4[3 * p + 2];
        float4 g  = s4[p];

        float uu[12] = {ua.x, ua.y, ua.z, ua.w, ub.x, ub.y, ub.z, ub.w,
                        uc.x, uc.y, uc.z, uc.w};
        float vv[12] = {va.x, va.y, va.z, va.w, vb.x, vb.y, vb.z, vb.w,
                        vc.x, vc.y, vc.z, vc.w};
        float ww[12] = {wa.x, wa.y, wa.z, wa.w, wb.x, wb.y, wb.z, wb.w,
                        wc.x, wc.y, wc.z, wc.w};
        float gg[4] = {g.x, g.y, g.z, g.w};

#pragma unroll
        for (int k = 0; k < 4; ++k) {
            float e0 = uu[3 * k + 0];
            float e1 = vv[3 * k + 1];
            float e2 = ww[3 * k + 2];
            float e3 = 0.5f * (uu[3 * k + 1] + vv[3 * k + 0]);
            float e4 = 0.5f * (uu[3 * k + 2] + ww[3 * k + 0]);
            float e5 = 0.5f * (ww[3 * k + 1] + vv[3 * k + 2]);

            float q = e0 * (C.b[0][0] * e0 + C.b[0][1] * e1 + C.b[0][2] * e2)
                    + e1 * (C.b[1][0] * e0 + C.b[1][1] * e1 + C.b[1][2] * e2)
                    + e2 * (C.b[2][0] * e0 + C.b[2][1] * e1 + C.b[2][2] * e2)
                    + C.s * (e3 * e3 + e4 * e4 + e5 * e5);

            bool m = gg[k] < 1e-8f;
            float qm = m ? q : 0.0f;
            sumq2 += qm * qm;
            cnt   += m ? 1.0f : 0.0f;
        }
    }

    // Tail (n not divisible by 4) — handled by global thread 0 only.
    if (blockIdx.x == 0 && threadIdx.x == 0) {
        for (int i = npack * 4; i < n; ++i) {
            float e0 = gu[3 * i + 0];
            float e1 = gv[3 * i + 1];
            float e2 = gw[3 * i + 2];
            float e3 = 0.5f * (gu[3 * i + 1] + gv[3 * i + 0]);
            float e4 = 0.5f * (gu[3 * i + 2] + gw[3 * i + 0]);
            float e5 = 0.5f * (gw[3 * i + 1] + gv[3 * i + 2]);
            float q = e0 * (C.b[0][0] * e0 + C.b[0][1] * e1 + C.b[0][2] * e2)
                    + e1 * (C.b[1][0] * e0 + C.b[1][1] * e1 + C.b[1][2] * e2)
                    + e2 * (C.b[2][0] * e0 + C.b[2][1] * e1 + C.b[2][2] * e2)
                    + C.s * (e3 * e3 + e4 * e4 + e5 * e5);
            bool m = gs[i] < 1e-8f;
            float qm = m ? q : 0.0f;
            sumq2 += qm * qm;
            cnt   += m ? 1.0f : 0.0f;
        }
    }

    // Wave (64-lane) shuffle reduction
#pragma unroll
    for (int off = 32; off > 0; off >>= 1) {
        sumq2 += __shfl_down(sumq2, off);
        cnt   += __shfl_down(cnt, off);
    }

    __shared__ float ssum[4], scnt[4];
    const int wave = threadIdx.x >> 6;
    const int lane = threadIdx.x & 63;
    if (lane == 0) { ssum[wave] = sumq2; scnt[wave] = cnt; }
    __syncthreads();
    if (threadIdx.x == 0) {
        float s2 = 0.0f, c2 = 0.0f;
#pragma unroll
        for (int i = 0; i < 4; ++i) { s2 += ssum[i]; c2 += scnt[i]; }
        atomicAdd(&ws[0], s2);
        atomicAdd(&ws[1], c2);
    }
}

__global__ void biomech_finalize(const float* __restrict__ ws,
                                 float* __restrict__ out)
{
    if (threadIdx.x == 0 && blockIdx.x == 0) {
        out[0] = sqrtf(ws[0]) / ws[1];
    }
}

extern "C" void kernel_launch(void* const* d_in, const int* in_sizes, int n_in,
                              void* d_out, int out_size, void* d_ws, size_t ws_size,
                              hipStream_t stream) {
    const float* gu = (const float*)d_in[0];
    const float* gv = (const float*)d_in[1];
    const float* gw = (const float*)d_in[2];
    const float* gs = (const float*)d_in[3];
    float* ws = (float*)d_ws;
    float* out = (float*)d_out;

    const int n = in_sizes[3];      // number of points (gt_sdf length)
    const int npack = n / 4;

    // ws is re-poisoned to 0xAA before every launch — zero the accumulators.
    hipMemsetAsync(d_ws, 0, 2 * sizeof(float), stream);

    const int block = 256;
    int grid = (npack + block - 1) / block;
    if (grid > 4096) grid = 4096;
    if (grid < 1) grid = 1;

    biomech_reduce<<<grid, block, 0, stream>>>(gu, gv, gw, gs, ws, npack, n, g_C);
    biomech_finalize<<<1, 64, 0, stream>>>(ws, out);
}

// Round 2
// 178.655 us; speedup vs baseline: 1.3165x; 1.3165x over previous
//
#include <hip/hip_runtime.h>
#include <math.h>

// ---------------------------------------------------------------------------
// Host-side: build stiffness matrix C = inv(Ci) in double precision (faithful
// to np.linalg.inv of the block-diagonal compliance matrix).
// ---------------------------------------------------------------------------
struct CParams {
    float b[3][3];  // inverse of the upper-left 3x3 compliance block
    float s;        // shear stiffness diagonal = Ep / (2*(1+vp)) = 0.075
};

static CParams make_C() {
    const double vp = 0.4, Ep = 0.21;
    double A[3][3] = {
        {1.0 / Ep, -vp / Ep, -vp / Ep},
        {-vp / Ep, 1.0 / Ep, -vp / Ep},
        {-vp,      -vp,      1.0 / Ep},   // note: -vp, NOT -vp/Ep (faithful)
    };
    double inv[3][3] = {{1, 0, 0}, {0, 1, 0}, {0, 0, 1}};
    for (int col = 0; col < 3; ++col) {
        int piv = col;
        for (int r = col + 1; r < 3; ++r)
            if (fabs(A[r][col]) > fabs(A[piv][col])) piv = r;
        if (piv != col) {
            for (int c = 0; c < 3; ++c) {
                double t = A[col][c]; A[col][c] = A[piv][c]; A[piv][c] = t;
                t = inv[col][c]; inv[col][c] = inv[piv][c]; inv[piv][c] = t;
            }
        }
        double d = A[col][col];
        for (int c = 0; c < 3; ++c) { A[col][c] /= d; inv[col][c] /= d; }
        for (int r = 0; r < 3; ++r) {
            if (r == col) continue;
            double f = A[r][col];
            for (int c = 0; c < 3; ++c) {
                A[r][c] -= f * A[col][c];
                inv[r][c] -= f * inv[col][c];
            }
        }
    }
    CParams p;
    for (int i = 0; i < 3; ++i)
        for (int j = 0; j < 3; ++j)
            p.b[i][j] = (float)inv[i][j];
    p.s = (float)(Ep / (2.0 * (1.0 + vp)));
    return p;
}

static const CParams g_C = make_C();

#define MAXB 2048  // max blocks / partial slots

__device__ __forceinline__ void accum_packet(
    const float4* u4, const float4* v4, const float4* w4, const float4* s4,
    int p, const CParams& C, float& sumq2, float& cnt)
{
    float4 ua = u4[3 * p], ub = u4[3 * p + 1], uc = u4[3 * p + 2];
    float4 va = v4[3 * p], vb = v4[3 * p + 1], vc = v4[3 * p + 2];
    float4 wa = w4[3 * p], wb = w4[3 * p + 1], wc = w4[3 * p + 2];
    float4 g  = s4[p];

    float uu[12] = {ua.x, ua.y, ua.z, ua.w, ub.x, ub.y, ub.z, ub.w,
                    uc.x, uc.y, uc.z, uc.w};
    float vv[12] = {va.x, va.y, va.z, va.w, vb.x, vb.y, vb.z, vb.w,
                    vc.x, vc.y, vc.z, vc.w};
    float ww[12] = {wa.x, wa.y, wa.z, wa.w, wb.x, wb.y, wb.z, wb.w,
                    wc.x, wc.y, wc.z, wc.w};
    float gg[4] = {g.x, g.y, g.z, g.w};

#pragma unroll
    for (int k = 0; k < 4; ++k) {
        float e0 = uu[3 * k + 0];
        float e1 = vv[3 * k + 1];
        float e2 = ww[3 * k + 2];
        float e3 = 0.5f * (uu[3 * k + 1] + vv[3 * k + 0]);
        float e4 = 0.5f * (uu[3 * k + 2] + ww[3 * k + 0]);
        float e5 = 0.5f * (ww[3 * k + 1] + vv[3 * k + 2]);

        float q = e0 * (C.b[0][0] * e0 + C.b[0][1] * e1 + C.b[0][2] * e2)
                + e1 * (C.b[1][0] * e0 + C.b[1][1] * e1 + C.b[1][2] * e2)
                + e2 * (C.b[2][0] * e0 + C.b[2][1] * e1 + C.b[2][2] * e2)
                + C.s * (e3 * e3 + e4 * e4 + e5 * e5);

        bool m = gg[k] < 1e-8f;
        float qm = m ? q : 0.0f;
        sumq2 += qm * qm;
        cnt   += m ? 1.0f : 0.0f;
    }
}

// ---------------------------------------------------------------------------
// Main reduction: 2 packets per thread per outer iteration (20 float4 loads in
// flight), per-block partial -> direct store to d_ws (NO global atomics).
// ---------------------------------------------------------------------------
__global__ __launch_bounds__(256) void biomech_reduce(
    const float* __restrict__ gu, const float* __restrict__ gv,
    const float* __restrict__ gw, const float* __restrict__ gs,
    float* __restrict__ ws, int npack, int n, CParams C)
{
    const float4* u4 = (const float4*)gu;
    const float4* v4 = (const float4*)gv;
    const float4* w4 = (const float4*)gw;
    const float4* s4 = (const float4*)gs;

    float sumq2 = 0.0f;
    float cnt   = 0.0f;

    const int t = blockIdx.x * blockDim.x + threadIdx.x;
    const int T = gridDim.x * blockDim.x;

    for (int base = 0; base < npack; base += 2 * T) {
        int p0 = base + t;
        int p1 = p0 + T;
        if (p1 < npack) {
            // both in range — issue all 20 loads back-to-back
            accum_packet(u4, v4, w4, s4, p0, C, sumq2, cnt);
            accum_packet(u4, v4, w4, s4, p1, C, sumq2, cnt);
        } else {
            if (p0 < npack) accum_packet(u4, v4, w4, s4, p0, C, sumq2, cnt);
        }
    }

    // Tail (n not divisible by 4) — global thread 0 only.
    if (blockIdx.x == 0 && threadIdx.x == 0) {
        for (int i = npack * 4; i < n; ++i) {
            float e0 = gu[3 * i + 0];
            float e1 = gv[3 * i + 1];
            float e2 = gw[3 * i + 2];
            float e3 = 0.5f * (gu[3 * i + 1] + gv[3 * i + 0]);
            float e4 = 0.5f * (gu[3 * i + 2] + gw[3 * i + 0]);
            float e5 = 0.5f * (gw[3 * i + 1] + gv[3 * i + 2]);
            float q = e0 * (C.b[0][0] * e0 + C.b[0][1] * e1 + C.b[0][2] * e2)
                    + e1 * (C.b[1][0] * e0 + C.b[1][1] * e1 + C.b[1][2] * e2)
                    + e2 * (C.b[2][0] * e0 + C.b[2][1] * e1 + C.b[2][2] * e2)
                    + C.s * (e3 * e3 + e4 * e4 + e5 * e5);
            bool m = gs[i] < 1e-8f;
            float qm = m ? q : 0.0f;
            sumq2 += qm * qm;
            cnt   += m ? 1.0f : 0.0f;
        }
    }

    // Wave (64-lane) shuffle reduction
#pragma unroll
    for (int off = 32; off > 0; off >>= 1) {
        sumq2 += __shfl_down(sumq2, off);
        cnt   += __shfl_down(cnt, off);
    }

    __shared__ float ssum[4], scnt[4];
    const int wave = threadIdx.x >> 6;
    const int lane = threadIdx.x & 63;
    if (lane == 0) { ssum[wave] = sumq2; scnt[wave] = cnt; }
    __syncthreads();
    if (threadIdx.x == 0) {
        float s2 = 0.0f, c2 = 0.0f;
#pragma unroll
        for (int i = 0; i < 4; ++i) { s2 += ssum[i]; c2 += scnt[i]; }
        ws[blockIdx.x]        = s2;   // contention-free per-block store
        ws[MAXB + blockIdx.x] = c2;
    }
}

// ---------------------------------------------------------------------------
// Finalize: single block reduces nb partial pairs, writes sqrt(sum)/count.
// ---------------------------------------------------------------------------
__global__ __launch_bounds__(256) void biomech_finalize(
    const float* __restrict__ ws, float* __restrict__ out, int nb)
{
    float s = 0.0f, c = 0.0f;
    for (int i = threadIdx.x; i < nb; i += 256) {
        s += ws[i];
        c += ws[MAXB + i];
    }
#pragma unroll
    for (int off = 32; off > 0; off >>= 1) {
        s += __shfl_down(s, off);
        c += __shfl_down(c, off);
    }
    __shared__ float ssum[4], scnt[4];
    const int wave = threadIdx.x >> 6;
    const int lane = threadIdx.x & 63;
    if (lane == 0) { ssum[wave] = s; scnt[wave] = c; }
    __syncthreads();
    if (threadIdx.x == 0) {
        float s2 = ssum[0] + ssum[1] + ssum[2] + ssum[3];
        float c2 = scnt[0] + scnt[1] + scnt[2] + scnt[3];
        out[0] = sqrtf(s2) / c2;
    }
}

extern "C" void kernel_launch(void* const* d_in, const int* in_sizes, int n_in,
                              void* d_out, int out_size, void* d_ws, size_t ws_size,
                              hipStream_t stream) {
    const float* gu = (const float*)d_in[0];
    const float* gv = (const float*)d_in[1];
    const float* gw = (const float*)d_in[2];
    const float* gs = (const float*)d_in[3];
    float* ws = (float*)d_ws;
    float* out = (float*)d_out;

    const int n = in_sizes[3];      // number of points (gt_sdf length)
    const int npack = n / 4;

    const int block = 256;
    int grid = (npack + block - 1) / block;
    if (grid > MAXB) grid = MAXB;
    // safety: never exceed the workspace (needs 2*grid floats across a
    // MAXB-strided layout -> (MAXB+grid)*4 bytes)
    while (grid > 1 && (size_t)(MAXB + grid) * sizeof(float) > ws_size) grid >>= 1;
    if (grid < 1) grid = 1;

    biomech_reduce<<<grid, block, 0, stream>>>(gu, gv, gw, gs, ws, npack, n, g_C);
    biomech_finalize<<<1, block, 0, stream>>>(ws, out, grid);
}

// Round 5
// 178.171 us; speedup vs baseline: 1.3201x; 1.0027x over previous
//
#include <hip/hip_runtime.h>
#include <math.h>

// ---------------------------------------------------------------------------
// Host-side: build stiffness matrix C = inv(Ci) in double precision (faithful
// to np.linalg.inv of the block-diagonal compliance matrix).
// ---------------------------------------------------------------------------
struct CParams {
    float b[3][3];  // inverse of the upper-left 3x3 compliance block
    float s;        // shear stiffness diagonal = Ep / (2*(1+vp)) = 0.075
};

static CParams make_C() {
    const double vp = 0.4, Ep = 0.21;
    double A[3][3] = {
        {1.0 / Ep, -vp / Ep, -vp / Ep},
        {-vp / Ep, 1.0 / Ep, -vp / Ep},
        {-vp,      -vp,      1.0 / Ep},   // note: -vp, NOT -vp/Ep (faithful)
    };
    double inv[3][3] = {{1, 0, 0}, {0, 1, 0}, {0, 0, 1}};
    for (int col = 0; col < 3; ++col) {
        int piv = col;
        for (int r = col + 1; r < 3; ++r)
            if (fabs(A[r][col]) > fabs(A[piv][col])) piv = r;
        if (piv != col) {
            for (int c = 0; c < 3; ++c) {
                double t = A[col][c]; A[col][c] = A[piv][c]; A[piv][c] = t;
                t = inv[col][c]; inv[col][c] = inv[piv][c]; inv[piv][c] = t;
            }
        }
        double d = A[col][col];
        for (int c = 0; c < 3; ++c) { A[col][c] /= d; inv[col][c] /= d; }
        for (int r = 0; r < 3; ++r) {
            if (r == col) continue;
            double f = A[r][col];
            for (int c = 0; c < 3; ++c) {
                A[r][c] -= f * A[col][c];
                inv[r][c] -= f * inv[col][c];
            }
        }
    }
    CParams p;
    for (int i = 0; i < 3; ++i)
        for (int j = 0; j < 3; ++j)
            p.b[i][j] = (float)inv[i][j];
    p.s = (float)(Ep / (2.0 * (1.0 + vp)));
    return p;
}

static const CParams g_C = make_C();

#define MAXB 2048   // partial-sum slots in workspace
#define TPB  256    // threads per block (4 waves)
#define TILE 256    // points per wave-group
#define F4A  192    // float4s per array per tile (256 pts * 3 floats / 4)

#define ZERO4 make_float4(0.0f, 0.0f, 0.0f, 0.0f)

// ---------------------------------------------------------------------------
// Main reduction. Coalesced loads + LDS staging + barrier-enforced ordering:
//   - per 256-point group, each wave issues 9 fully-coalesced float4 loads
//     (3 per gradient array) + 4 coalesced sdf loads; next group's loads are
//     register-prefetched (all regs zero-initialized — no UB).
//   - float4 stores into a per-wave LDS slice; __syncthreads() BETWEEN the
//     stores and the float regather reads. The barrier (HW fence) enforces
//     RAW/WAR ordering that TBAA-based alias analysis cannot break — float4
//     stores vs float loads carry different TBAA and round-4 showed a ~4.8%
//     sum deficit consistent with reads scheduled before writes landed.
//   - regather: lane p reads floats 3p..3p+2 — stride-3 across lanes covers
//     each bank once per 32 words (gcd(3,32)=1): conflict-free.
// Loop iterates on the BLOCK's base group so barriers sit in uniform control
// flow. 36 KB LDS/block -> 4 blocks/CU (16 waves/CU). Grid 1024 co-resident.
// ---------------------------------------------------------------------------
__global__ __launch_bounds__(TPB) void biomech_reduce(
    const float* __restrict__ gu, const float* __restrict__ gv,
    const float* __restrict__ gw, const float* __restrict__ gs,
    float* __restrict__ ws, int n, CParams C)
{
    __shared__ float4 buf[TPB / 64][3][F4A];

    const int wave    = threadIdx.x >> 6;
    const int lane    = threadIdx.x & 63;
    const int nwaves  = gridDim.x * (TPB / 64);
    const int ngroups = n / TILE;

    const float4* u4 = (const float4*)gu;
    const float4* v4 = (const float4*)gv;
    const float4* w4 = (const float4*)gw;

    float sumq2 = 0.0f, cnt = 0.0f;

    float4 pu0 = ZERO4, pu1 = ZERO4, pu2 = ZERO4;
    float4 pv0 = ZERO4, pv1 = ZERO4, pv2 = ZERO4;
    float4 pw0 = ZERO4, pw1 = ZERO4, pw2 = ZERO4;
    float  ps0 = 1.0f, ps1 = 1.0f, ps2 = 1.0f, ps3 = 1.0f;  // mask-false

    {
        const int g = blockIdx.x * (TPB / 64) + wave;
        if (g < ngroups) {
            const int b  = g * F4A;
            const int sb = g * TILE;
            pu0 = u4[b + lane]; pu1 = u4[b + 64 + lane]; pu2 = u4[b + 128 + lane];
            pv0 = v4[b + lane]; pv1 = v4[b + 64 + lane]; pv2 = v4[b + 128 + lane];
            pw0 = w4[b + lane]; pw1 = w4[b + 64 + lane]; pw2 = w4[b + 128 + lane];
            ps0 = gs[sb + lane];       ps1 = gs[sb + 64 + lane];
            ps2 = gs[sb + 128 + lane]; ps3 = gs[sb + 192 + lane];
        }
    }

    // gb = block's base group — identical for all threads in the block, so
    // the loop (and its barriers) is block-uniform.
    for (int gb = blockIdx.x * (TPB / 64); gb < ngroups; gb += nwaves) {
        const int g  = gb + wave;
        const int gn = g + nwaves;

        float4 nu0 = ZERO4, nu1 = ZERO4, nu2 = ZERO4;
        float4 nv0 = ZERO4, nv1 = ZERO4, nv2 = ZERO4;
        float4 nw0 = ZERO4, nw1 = ZERO4, nw2 = ZERO4;
        float  ns0 = 1.0f, ns1 = 1.0f, ns2 = 1.0f, ns3 = 1.0f;
        if (gn < ngroups) {  // prefetch next group while this one computes
            const int b  = gn * F4A;
            const int sb = gn * TILE;
            nu0 = u4[b + lane]; nu1 = u4[b + 64 + lane]; nu2 = u4[b + 128 + lane];
            nv0 = v4[b + lane]; nv1 = v4[b + 64 + lane]; nv2 = v4[b + 128 + lane];
            nw0 = w4[b + lane]; nw1 = w4[b + 64 + lane]; nw2 = w4[b + 128 + lane];
            ns0 = gs[sb + lane];       ns1 = gs[sb + 64 + lane];
            ns2 = gs[sb + 128 + lane]; ns3 = gs[sb + 192 + lane];
        }

        // stage current group into this wave's LDS slice
        if (g < ngroups) {
            buf[wave][0][lane] = pu0; buf[wave][0][64 + lane] = pu1; buf[wave][0][128 + lane] = pu2;
            buf[wave][1][lane] = pv0; buf[wave][1][64 + lane] = pv1; buf[wave][1][128 + lane] = pv2;
            buf[wave][2][lane] = pw0; buf[wave][2][64 + lane] = pw1; buf[wave][2][128 + lane] = pw2;
        }

        __syncthreads();   // RAW fence: stores visible before regather reads

        if (g < ngroups) {
            const float* bu = (const float*)&buf[wave][0][0];
            const float* bv = (const float*)&buf[wave][1][0];
            const float* bw = (const float*)&buf[wave][2][0];
            const float sd[4] = {ps0, ps1, ps2, ps3};

#pragma unroll
            for (int k = 0; k < 4; ++k) {
                const int p = lane + (k << 6);     // point index within tile
                float u0 = bu[3 * p], u1 = bu[3 * p + 1], u2 = bu[3 * p + 2];
                float v0 = bv[3 * p], v1 = bv[3 * p + 1], v2 = bv[3 * p + 2];
                float w0 = bw[3 * p], w1 = bw[3 * p + 1], w2 = bw[3 * p + 2];

                float e0 = u0, e1 = v1, e2 = w2;
                float e3 = 0.5f * (u1 + v0);
                float e4 = 0.5f * (u2 + w0);
                float e5 = 0.5f * (w1 + v2);

                float q = e0 * (C.b[0][0] * e0 + C.b[0][1] * e1 + C.b[0][2] * e2)
                        + e1 * (C.b[1][0] * e0 + C.b[1][1] * e1 + C.b[1][2] * e2)
                        + e2 * (C.b[2][0] * e0 + C.b[2][1] * e1 + C.b[2][2] * e2)
                        + C.s * (e3 * e3 + e4 * e4 + e5 * e5);

                bool m = sd[k] < 1e-8f;
                float qm = m ? q : 0.0f;
                sumq2 += qm * qm;
                cnt   += m ? 1.0f : 0.0f;
            }
        }

        __syncthreads();   // WAR fence: reads done before next iter's stores

        pu0 = nu0; pu1 = nu1; pu2 = nu2;
        pv0 = nv0; pv1 = nv1; pv2 = nv2;
        pw0 = nw0; pw1 = nw1; pw2 = nw2;
        ps0 = ns0; ps1 = ns1; ps2 = ns2; ps3 = ns3;
    }

    // Tail (n not divisible by TILE) — global thread 0 only.
    if (blockIdx.x == 0 && threadIdx.x == 0) {
        for (int i = (n / TILE) * TILE; i < n; ++i) {
            float e0 = gu[3 * i + 0];
            float e1 = gv[3 * i + 1];
            float e2 = gw[3 * i + 2];
            float e3 = 0.5f * (gu[3 * i + 1] + gv[3 * i + 0]);
            float e4 = 0.5f * (gu[3 * i + 2] + gw[3 * i + 0]);
            float e5 = 0.5f * (gw[3 * i + 1] + gv[3 * i + 2]);
            float q = e0 * (C.b[0][0] * e0 + C.b[0][1] * e1 + C.b[0][2] * e2)
                    + e1 * (C.b[1][0] * e0 + C.b[1][1] * e1 + C.b[1][2] * e2)
                    + e2 * (C.b[2][0] * e0 + C.b[2][1] * e1 + C.b[2][2] * e2)
                    + C.s * (e3 * e3 + e4 * e4 + e5 * e5);
            bool m = gs[i] < 1e-8f;
            float qm = m ? q : 0.0f;
            sumq2 += qm * qm;
            cnt   += m ? 1.0f : 0.0f;
        }
    }

    // Wave (64-lane) shuffle reduction
#pragma unroll
    for (int off = 32; off > 0; off >>= 1) {
        sumq2 += __shfl_down(sumq2, off);
        cnt   += __shfl_down(cnt, off);
    }

    __shared__ float ssum[4], scnt[4];
    if (lane == 0) { ssum[wave] = sumq2; scnt[wave] = cnt; }
    __syncthreads();
    if (threadIdx.x == 0) {
        float s2 = 0.0f, c2 = 0.0f;
#pragma unroll
        for (int i = 0; i < 4; ++i) { s2 += ssum[i]; c2 += scnt[i]; }
        ws[blockIdx.x]        = s2;   // contention-free per-block store
        ws[MAXB + blockIdx.x] = c2;
    }
}

// ---------------------------------------------------------------------------
// Finalize: single block reduces nb partial pairs, writes sqrt(sum)/count.
// ---------------------------------------------------------------------------
__global__ __launch_bounds__(256) void biomech_finalize(
    const float* __restrict__ ws, float* __restrict__ out, int nb)
{
    float s = 0.0f, c = 0.0f;
    for (int i = threadIdx.x; i < nb; i += 256) {
        s += ws[i];
        c += ws[MAXB + i];
    }
#pragma unroll
    for (int off = 32; off > 0; off >>= 1) {
        s += __shfl_down(s, off);
        c += __shfl_down(c, off);
    }
    __shared__ float ssum[4], scnt[4];
    const int wave = threadIdx.x >> 6;
    const int lane = threadIdx.x & 63;
    if (lane == 0) { ssum[wave] = s; scnt[wave] = c; }
    __syncthreads();
    if (threadIdx.x == 0) {
        float s2 = ssum[0] + ssum[1] + ssum[2] + ssum[3];
        float c2 = scnt[0] + scnt[1] + scnt[2] + scnt[3];
        out[0] = sqrtf(s2) / c2;
    }
}

extern "C" void kernel_launch(void* const* d_in, const int* in_sizes, int n_in,
                              void* d_out, int out_size, void* d_ws, size_t ws_size,
                              hipStream_t stream) {
    const float* gu = (const float*)d_in[0];
    const float* gv = (const float*)d_in[1];
    const float* gw = (const float*)d_in[2];
    const float* gs = (const float*)d_in[3];
    float* ws = (float*)d_ws;
    float* out = (float*)d_out;

    const int n = in_sizes[3];      // number of points (gt_sdf length)
    const int ngroups = n / TILE;
    const int wpb = TPB / 64;

    int grid = (ngroups + wpb - 1) / wpb;
    if (grid > 1024) grid = 1024;   // 4 blocks/CU (36 KB LDS each) co-resident
    if (grid > MAXB) grid = MAXB;
    while (grid > 1 && (size_t)(MAXB + grid) * sizeof(float) > ws_size) grid >>= 1;
    if (grid < 1) grid = 1;

    biomech_reduce<<<grid, TPB, 0, stream>>>(gu, gv, gw, gs, ws, n, g_C);
    biomech_finalize<<<1, 256, 0, stream>>>(ws, out, grid);
}